// Round 17
// baseline (83.475 us; speedup 1.0000x reference)
//
#include <hip/hip_runtime.h>

#define DN 384
#define DS 512
#define DMSA 64
#define DH 32
#define DP 128

typedef __bf16 bf16x8 __attribute__((ext_vector_type(8)));
typedef __bf16 bf16x4 __attribute__((ext_vector_type(4)));
typedef float f32x4 __attribute__((ext_vector_type(4)));
typedef float f32x16 __attribute__((ext_vector_type(16)));

// ws layout (bytes)
#define OFF_BT    12582912u
#define OFF_WT    25165824u   // wt bf16 [kk 64][p 128][ks 16] = 256KB
#define OFF_INV   25427968u   // 1 f32
#define OFF_CNT   25428032u   // [scnt, ncnt, ninv]
#define OFF_SPERM 25428224u   // 512 i32
#define OFF_NPERM 25430272u   // 392 i32 (padded with 0)
#define OFF_INVN  25432064u   // 384 i32: indices with mask==0
#define OFF_TRASH 25433600u   // 32KB float trash for invalid-pair stores

__device__ __forceinline__ void async16(const void* g, void* l) {
  __builtin_amdgcn_global_load_lds((const __attribute__((address_space(1))) unsigned*)g,
                                   (__attribute__((address_space(3))) unsigned*)l, 16, 0, 0);
}

// ---------------------------------------------------------------------------
// prep: mask compaction (ballot-parallel, active AND inactive lists) +
// w_out -> wt [kk][p][ks].
// ---------------------------------------------------------------------------
__global__ __launch_bounds__(128) void prep_kernel(const void* __restrict__ mask_raw,
                                                   const void* __restrict__ msa_mask_raw,
                                                   const float* __restrict__ w_out,
                                                   __bf16* __restrict__ wt,
                                                   float* __restrict__ invp,
                                                   int* __restrict__ cnt,
                                                   int* __restrict__ sperm,
                                                   int* __restrict__ nperm,
                                                   int* __restrict__ invn) {
  const int blk = blockIdx.x;
  const int tid = threadIdx.x;
  if (blk == 0) {
    __shared__ int sh[128];
    __shared__ float sv[512];
    __shared__ int sp[512];
    __shared__ int csh;
    const unsigned int* u = (const unsigned int*)msa_mask_raw;
    sh[tid] = (u[tid] > 1u) ? 1 : 0;
    __syncthreads();
    for (int off = 64; off > 0; off >>= 1) {
      if (tid < off) sh[tid] |= sh[tid + off];
      __syncthreads();
    }
    const int int_mode = (sh[0] == 0);
    __syncthreads();
    for (int q = tid; q < DS; q += 128) {
      float v;
      if (int_mode) v = (((const int*)msa_mask_raw)[q] != 0) ? 1.f : 0.f;
      else          v = (((const unsigned char*)msa_mask_raw)[q] != 0) ? 1.f : 0.f;
      sv[q] = v;
    }
    __syncthreads();
    if (tid < 64) {
      int base = 0;
#pragma unroll
      for (int r = 0; r < 8; ++r) {
        const int s = r * 64 + tid;
        const bool v = (sv[s] != 0.f);
        const unsigned long long bal = __ballot(v);
        const int below = __popcll(bal & ((1ull << tid) - 1ull));
        if (v) sp[base + below] = s;
        base += __popcll(bal);
      }
      if (tid == 0) {
        csh = base;
        cnt[0] = base;
        float num = (float)base;
        if (num < 1e-5f) num = 1e-5f;
        invp[0] = 1.0f / num;
      }
    }
    __syncthreads();
    const int c = csh;
    for (int q = tid; q < c; q += 128) sperm[q] = sp[q];
  } else if (blk == 1) {
    __shared__ int sh[128];
    __shared__ float sv[384];
    __shared__ int sp[384];
    __shared__ int sq[384];
    __shared__ int csh, ish;
    const unsigned int* u = (const unsigned int*)mask_raw;
    sh[tid] = (tid < 96) ? ((u[tid] > 1u) ? 1 : 0) : 0;
    __syncthreads();
    for (int off = 64; off > 0; off >>= 1) {
      if (tid < off) sh[tid] |= sh[tid + off];
      __syncthreads();
    }
    const int int_mode = (sh[0] == 0);
    __syncthreads();
    for (int q = tid; q < DN; q += 128) {
      float v;
      if (int_mode) v = (((const int*)mask_raw)[q] != 0) ? 1.f : 0.f;
      else          v = (((const unsigned char*)mask_raw)[q] != 0) ? 1.f : 0.f;
      sv[q] = v;
    }
    __syncthreads();
    if (tid < 64) {
      int base = 0, ibase = 0;
#pragma unroll
      for (int r = 0; r < 6; ++r) {
        const int n = r * 64 + tid;
        const bool v = (sv[n] != 0.f);
        const unsigned long long bal = __ballot(v);
        const int below = __popcll(bal & ((1ull << tid) - 1ull));
        if (v) sp[base + below] = n;
        else   sq[ibase + (tid - below - __popcll(~bal & ~((~0ull) << 0)) * 0)
                  ] = n;  // placeholder, fixed below
        base += __popcll(bal);
        ibase += 64 - __popcll(bal);
      }
      if (tid == 0) { csh = base; ish = ibase; cnt[1] = base; cnt[2] = ibase; }
    }
    __syncthreads();
    // redo inactive list cleanly (the lane math above for sq is unreliable)
    if (tid < 64) {
      int ibase = 0;
#pragma unroll
      for (int r = 0; r < 6; ++r) {
        const int n = r * 64 + tid;
        const bool iv = (sv[n] == 0.f);
        const unsigned long long bal = __ballot(iv);
        const int below = __popcll(bal & ((1ull << tid) - 1ull));
        if (iv) sq[ibase + below] = n;
        ibase += __popcll(bal);
      }
    }
    __syncthreads();
    const int c = csh, ic = ish;
    for (int q = tid; q < 392; q += 128) nperm[q] = (q < c) ? sp[q] : 0;
    for (int q = tid; q < ic; q += 128) invn[q] = sq[q];
  } else {
    const int p = blk - 2;                        // 0..127
    const int kk = tid >> 1, ks0 = (tid & 1) * 8; // 16B run
    bf16x8 pk;
#pragma unroll
    for (int j = 0; j < 8; ++j) {
      const int kp = kk * 16 + ks0 + j;           // k' = e*32+d
      const int d = kp & 31, e = kp >> 5;
      pk[j] = (__bf16)w_out[(size_t)(d * 32 + e) * DP + p];
    }
    *(bf16x8*)(wt + ((size_t)kk * 128 + p) * 16 + ks0) = pk;
  }
}

// ---------------------------------------------------------------------------
// ln_proj: blocks b < 2*ntile8 do compacted LN+projection; remaining blocks
// fill ONLY invalid pairs with b_out, run-granular (no per-store tests):
//   phase a: rows with mask[i]==0 -> stream whole row (const-div addressing)
//   phase b: valid-i x invalid-j pairs -> one div per 512B contiguous run
// ---------------------------------------------------------------------------
__global__ __launch_bounds__(256) void ln_proj_kernel(const float* __restrict__ msa,
                                                      const float* __restrict__ gamma,
                                                      const float* __restrict__ beta,
                                                      const float* __restrict__ w_hidden,
                                                      const float* __restrict__ invp,
                                                      const int* __restrict__ cnt,
                                                      const int* __restrict__ sperm,
                                                      const int* __restrict__ nperm,
                                                      const int* __restrict__ invn,
                                                      const float* __restrict__ b_out,
                                                      float* __restrict__ out,
                                                      __bf16* __restrict__ at,
                                                      __bf16* __restrict__ bt) {
  __shared__ __align__(16) char lds[46080];
  char* xlb = lds;            // 256 rows x 144B (64 bf16 + 16B pad)
  char* whb = lds + 36864;    // 64 rows x 144B: wh[c][d] bf16

  const int tid = threadIdx.x;
  const int b = blockIdx.x;

  const int scnt = cnt[0], ncnt = cnt[1], ninv = cnt[2];
  const int ntile8 = ((ncnt + 7) >> 3) << 3;

  if (b >= 2 * ntile8) {
    const int nW = 832 - 2 * ntile8;              // >= 64
    const int fid = b - 2 * ntile8;
    const int gstride = nW * 256;
    const int gtid = fid * 256 + tid;
    const float4* bo4 = (const float4*)b_out;
    float4* o4 = (float4*)out;

    // phase a: full rows for mask[i]==0 (each row = 12288 float4)
    const int chunks_a = ninv * 12288;
    for (int q = gtid; q < chunks_a; q += gstride) {
      const int row = q / 12288;                  // division by constant
      const int off = q - row * 12288;
      o4[(size_t)invn[row] * 12288 + off] = bo4[off & 31];
    }
    // phase b: valid-i x invalid-j pairs, 32 float4 per pair
    const int pairs_b = ncnt * ninv;
    for (int p = gtid; p < pairs_b; p += gstride) {
      const int ii = p / ninv;                    // one runtime div per 512B
      const int jj = p - ii * ninv;
      const size_t base = ((size_t)nperm[ii] * DN + invn[jj]) * 32;
#pragma unroll
      for (int r = 0; r < 32; ++r) o4[base + r] = bo4[r];
    }
    return;
  }

  const int cn = b >> 1;
  const int hf = b & 1;

  // stage w_hidden^T: wh[c][d] = w_hidden[d][c]
  for (int idx = tid; idx < 4096; idx += 256) {
    const int d = idx >> 6, c = idx & 63;
    *(__bf16*)(whb + c * 144 + d * 2) = (__bf16)w_hidden[idx];
  }

  const int cs = (hf << 8) + tid;
  const bool act = (cn < ncnt) && (cs < scnt);

  if (act) {
    const int n = nperm[cn];
    const int s = sperm[cs];
    const float* mp = msa + ((size_t)s * DN + n) * DMSA;
    float x[64];
    float sum = 0.f, sq = 0.f;
#pragma unroll
    for (int q = 0; q < 16; ++q) {
      float4 v = ((const float4*)mp)[q];
      x[4 * q + 0] = v.x; x[4 * q + 1] = v.y; x[4 * q + 2] = v.z; x[4 * q + 3] = v.w;
      sum += v.x + v.y + v.z + v.w;
      sq  += v.x * v.x + v.y * v.y + v.z * v.z + v.w * v.w;
    }
    const float mu = sum * (1.f / 64.f);
    const float var = sq * (1.f / 64.f) - mu * mu;
    const float rstd = rsqrtf(var + 1e-5f);
#pragma unroll
    for (int c8 = 0; c8 < 8; ++c8) {
      bf16x8 pk;
#pragma unroll
      for (int j = 0; j < 8; ++j) {
        const int d = c8 * 8 + j;
        pk[j] = (__bf16)((x[d] - mu) * rstd * gamma[d] + beta[d]);
      }
      *(bf16x8*)(xlb + tid * 144 + c8 * 16) = pk;
    }
  } else {
    const bf16x8 z = {};
#pragma unroll
    for (int c8 = 0; c8 < 8; ++c8)
      *(bf16x8*)(xlb + tid * 144 + c8 * 16) = z;
  }
  __syncthreads();

  // ---- MFMA: wave w owns rows w*64..+64; C[row=cs][col=c], K=64 ----
  const int l = tid & 63, w = tid >> 6;
  const int lr = l & 15, lk = l >> 4;

  bf16x8 bfr[4][2];
#pragma unroll
  for (int fj = 0; fj < 4; ++fj)
#pragma unroll
    for (int kk = 0; kk < 2; ++kk)
      bfr[fj][kk] = *(const bf16x8*)(whb + (fj * 16 + lr) * 144 + (kk * 4 + lk) * 16);

  f32x4 acc[4][4];
#pragma unroll
  for (int i = 0; i < 4; ++i)
#pragma unroll
    for (int j = 0; j < 4; ++j) acc[i][j] = (f32x4){0.f, 0.f, 0.f, 0.f};

#pragma unroll
  for (int fi = 0; fi < 4; ++fi) {
    bf16x8 af[2];
#pragma unroll
    for (int kk = 0; kk < 2; ++kk)
      af[kk] = *(const bf16x8*)(xlb + (w * 64 + fi * 16 + lr) * 144 + (kk * 4 + lk) * 16);
#pragma unroll
    for (int fj = 0; fj < 4; ++fj)
#pragma unroll
      for (int kk = 0; kk < 2; ++kk)
        acc[fi][fj] = __builtin_amdgcn_mfma_f32_16x16x32_bf16(af[kk], bfr[fj][kk], acc[fi][fj], 0, 0, 0);
  }

  // ---- epilogue: a scaled by inv; packed 8B stores at compacted cs ----
  const float inv = invp[0];
#pragma unroll
  for (int fi = 0; fi < 4; ++fi) {
    const int sg = (hf << 8) + w * 64 + fi * 16 + lk * 4;
#pragma unroll
    for (int fj = 0; fj < 4; ++fj) {
      const int c = fj * 16 + lr;
      bf16x4 pk;
      if (fj < 2) {
#pragma unroll
        for (int r = 0; r < 4; ++r) pk[r] = (__bf16)(acc[fi][fj][r] * inv);
        *(bf16x4*)(at + ((size_t)cn * DH + c) * DS + sg) = pk;
      } else {
#pragma unroll
        for (int r = 0; r < 4; ++r) pk[r] = (__bf16)acc[fi][fj][r];
        *(bf16x4*)(bt + ((size_t)cn * DH + (c - 32)) * DS + sg) = pk;
      }
    }
  }
}

// ---------------------------------------------------------------------------
// fused (r13-best, unchanged): grid 2304, blocks orig < tiles^2 map via
// bijective XCD swizzle; rest exit instantly. GEMM1 256x256 x K=64*nh coarse
// dbuf loop -> op->LDS (swizzled) -> GEMM2 (2-window wt pipeline) ->
// scatter epilogue via nperm (invalid pairs -> trash).
// ---------------------------------------------------------------------------
__global__ __launch_bounds__(512, 2) void fused_kernel(const __bf16* __restrict__ at,
                                                       const __bf16* __restrict__ bt,
                                                       const __bf16* __restrict__ wt,
                                                       const int* __restrict__ cnt,
                                                       const int* __restrict__ nperm,
                                                       const float* __restrict__ b_out,
                                                       float* __restrict__ trash,
                                                       float* __restrict__ out) {
  __shared__ __align__(128) char smem[132096];

  const int tid = threadIdx.x;
  const int l = tid & 63, w = tid >> 6;
  const int lr = l & 15, lk = l >> 4;
  const int wr = w >> 2, wc = w & 3;

  const int scnt = cnt[0], ncnt = cnt[1];
  const int tiles = (ncnt + 7) >> 3;
  const int nwg = tiles * tiles;
  const int orig = blockIdx.x;
  if (orig >= nwg) return;

  // bijective XCD swizzle within [0, nwg)
  const int xcd = orig & 7;
  const int qq = nwg >> 3, rr = nwg & 7;
  const int wgid = (xcd < rr ? xcd * (qq + 1) : rr * (qq + 1) + (xcd - rr) * qq) + (orig >> 3);
  const int bx = wgid % tiles;
  const int by = wgid / tiles;

  int nh = (scnt + 63) >> 6;
  if (nh < 1) nh = 1;

  // staging source pointers (pre-swizzled: LDS[row][chl] <- logical chl^(row&7))
  const __bf16* gA[4];
  const __bf16* gB[4];
#pragma unroll
  for (int q = 0; q < 4; ++q) {
    const int idx = q * 512 + tid;
    const int row = idx >> 3, chl = idx & 7;
    const int src = (chl ^ (row & 7)) * 8;
    gA[q] = at + (size_t)(bx * 256 + row) * 512 + src;
    gB[q] = bt + (size_t)(by * 256 + row) * 512 + src;
  }

  f32x4 acc[8][4];
#pragma unroll
  for (int i = 0; i < 8; ++i)
#pragma unroll
    for (int j = 0; j < 4; ++j) acc[i][j] = (f32x4){0.f, 0.f, 0.f, 0.f};

  auto STAGE = [&](int h, int s) {
    char* da = smem + s * 65536 + tid * 16;
    char* db = da + 32768;
    const int go = h * 64;
#pragma unroll
    for (int q = 0; q < 4; ++q) {
      async16(gA[q] + go, da + q * 8192);
      async16(gB[q] + go, db + q * 8192);
    }
  };

  STAGE(0, 0);
  asm volatile("s_waitcnt vmcnt(0)" ::: "memory");
  __builtin_amdgcn_s_barrier();

  for (int h = 0; h < nh; ++h) {
    const char* A = smem + (h & 1) * 65536;
    const char* B = A + 32768;
    if (h + 1 < nh) STAGE(h + 1, (h + 1) & 1);

#pragma unroll
    for (int kk = 0; kk < 2; ++kk) {
      bf16x8 af[8], bfr[4];
      const int c = kk * 4 + lk;
      const int phys = (c ^ (lr & 7)) * 16;
#pragma unroll
      for (int fj = 0; fj < 4; ++fj) {
        const int r = wc * 64 + fj * 16 + lr;
        bfr[fj] = *(const bf16x8*)(B + r * 128 + phys);
      }
#pragma unroll
      for (int fi = 0; fi < 8; ++fi) {
        const int r = wr * 128 + fi * 16 + lr;
        af[fi] = *(const bf16x8*)(A + r * 128 + phys);
      }
#pragma unroll
      for (int fi = 0; fi < 8; ++fi)
#pragma unroll
        for (int fj = 0; fj < 4; ++fj)
          acc[fi][fj] = __builtin_amdgcn_mfma_f32_16x16x32_bf16(af[fi], bfr[fj], acc[fi][fj], 0, 0, 0);
    }

    if (h + 1 < nh) {
      asm volatile("s_waitcnt vmcnt(0)" ::: "memory");
      __builtin_amdgcn_s_barrier();
    }
  }

  asm volatile("" ::: "memory");
  __builtin_amdgcn_s_barrier();
  asm volatile("" ::: "memory");

  // ---- op tile -> LDS bf16 as A2[pair][k'=e*32+d], chunk-XOR swizzled ----
#pragma unroll
  for (int fi = 0; fi < 8; ++fi) {
    const int i_l = wr * 4 + (fi >> 1);
#pragma unroll
    for (int fj = 0; fj < 4; ++fj) {
      const int col = wc * 64 + fj * 16 + lr;
      const int j_l = col >> 5, e = col & 31;
      const int pair = i_l * 8 + j_l;
      const int cw = e * 4 + (fi & 1) * 2 + (lk >> 1);
      const int phys = cw ^ (e & 7);
      bf16x4 pk;
      pk[0] = (__bf16)acc[fi][fj][0];
      pk[1] = (__bf16)acc[fi][fj][1];
      pk[2] = (__bf16)acc[fi][fj][2];
      pk[3] = (__bf16)acc[fi][fj][3];
      *(bf16x4*)(smem + pair * 2064 + phys * 16 + (lk & 1) * 8) = pk;
    }
  }

  // GEMM2 geometry; issue window-0 wt loads before the drain barrier (T14)
  const int mf = w >> 2, pf = w & 3;
  const int l31 = l & 31, lh = l >> 5;
  const __bf16* wb = wt + (size_t)(pf * 32 + l31) * 16 + lh * 8;  // + kk*2048

  bf16x8 bw[8], bn[8];
#pragma unroll
  for (int j = 0; j < 8; ++j)
    bw[j] = *(const bf16x8*)(wb + (size_t)j * 2048);

  asm volatile("s_waitcnt lgkmcnt(0)" ::: "memory");
  __builtin_amdgcn_s_barrier();

  // ---- GEMM2: 2-window (8+8) pipelined, 32x32x16 MFMA ----
  f32x16 acc2v;
#pragma unroll
  for (int q = 0; q < 16; ++q) acc2v[q] = 0.f;

  const char* aBase = smem + (mf * 32 + l31) * 2064;
#pragma unroll
  for (int wnd = 0; wnd < 8; ++wnd) {
    if (wnd < 7) {
#pragma unroll
      for (int j = 0; j < 8; ++j)
        bn[j] = *(const bf16x8*)(wb + (size_t)((wnd + 1) * 8 + j) * 2048);
    }
#pragma unroll
    for (int j = 0; j < 8; ++j) {
      const int kk = wnd * 8 + j;
      const int cw = kk * 2 + lh;
      const int phys = cw ^ ((kk >> 1) & 7);
      const bf16x8 a2 = *(const bf16x8*)(aBase + phys * 16);
      acc2v = __builtin_amdgcn_mfma_f32_32x32x16_bf16(a2, bw[j], acc2v, 0, 0, 0);
    }
#pragma unroll
    for (int j = 0; j < 8; ++j) bw[j] = bn[j];
  }

  // ---- scatter epilogue: valid pairs -> out[nperm[ii]][nperm[jj]] ----
  const int p = pf * 32 + l31;
  const float bo = b_out[p];
#pragma unroll
  for (int reg = 0; reg < 16; ++reg) {
    const int pair = mf * 32 + (reg & 3) + 8 * (reg >> 2) + 4 * lh;
    const int ii = bx * 8 + (pair >> 3);
    const int jj = by * 8 + (pair & 7);
    const bool valid = (ii < ncnt) && (jj < ncnt);
    const int ig = nperm[ii];
    const int jg = nperm[jj];
    float* dst = valid ? (out + ((size_t)ig * DN + jg) * DP + p)
                       : (trash + (tid * 16 + reg));
    *dst = acc2v[reg] + bo;
  }
}

extern "C" void kernel_launch(void* const* d_in, const int* in_sizes, int n_in,
                              void* d_out, int out_size, void* d_ws, size_t ws_size,
                              hipStream_t stream) {
  const float* msa      = (const float*)d_in[0];
  const void*  mask     = d_in[1];
  const void*  msa_mask = d_in[2];
  const float* gamma    = (const float*)d_in[3];
  const float* beta     = (const float*)d_in[4];
  const float* w_hidden = (const float*)d_in[5];
  const float* w_out    = (const float*)d_in[6];
  const float* b_out    = (const float*)d_in[7];
  float* out = (float*)d_out;

  char* ws = (char*)d_ws;
  __bf16* at    = (__bf16*)ws;
  __bf16* bt    = (__bf16*)(ws + OFF_BT);
  __bf16* wt    = (__bf16*)(ws + OFF_WT);
  float*  inv   = (float*)(ws + OFF_INV);
  int*    cnt   = (int*)(ws + OFF_CNT);
  int*    sperm = (int*)(ws + OFF_SPERM);
  int*    nperm = (int*)(ws + OFF_NPERM);
  int*    invn  = (int*)(ws + OFF_INVN);
  float*  trash = (float*)(ws + OFF_TRASH);

  prep_kernel<<<130, 128, 0, stream>>>(mask, msa_mask, w_out, wt, inv, cnt, sperm, nperm, invn);
  ln_proj_kernel<<<832, 256, 0, stream>>>(msa, gamma, beta, w_hidden, inv, cnt, sperm, nperm,
                                          invn, b_out, out, at, bt);
  fused_kernel<<<2304, 512, 0, stream>>>(at, bt, wt, cnt, nperm, b_out, trash, out);
}

// Round 18
// 78.366 us; speedup vs baseline: 1.0652x; 1.0652x over previous
//
#include <hip/hip_runtime.h>

#define DN 384
#define DS 512
#define DMSA 64
#define DH 32
#define DP 128

typedef __bf16 bf16x8 __attribute__((ext_vector_type(8)));
typedef __bf16 bf16x4 __attribute__((ext_vector_type(4)));
typedef float f32x4 __attribute__((ext_vector_type(4)));
typedef float f32x16 __attribute__((ext_vector_type(16)));

// ws layout (bytes)
#define OFF_BT    12582912u
#define OFF_WT    25165824u   // wt bf16 [kk 64][p 128][ks 16] = 256KB
#define OFF_INV   25427968u   // 1 f32
#define OFF_CNT   25428032u   // [scnt, ncnt]
#define OFF_SPERM 25428224u   // 512 i32
#define OFF_NPERM 25430272u   // 392 i32 (padded with 0)
#define OFF_MKF   25432064u   // 384 f32 mask-as-float
#define OFF_TRASH 25433600u   // 32KB float trash for invalid-pair stores

__device__ __forceinline__ void async16(const void* g, void* l) {
  __builtin_amdgcn_global_load_lds((const __attribute__((address_space(1))) unsigned*)g,
                                   (__attribute__((address_space(3))) unsigned*)l, 16, 0, 0);
}

// ---------------------------------------------------------------------------
// prep: mask compaction (ballot-parallel) + mkf + w_out -> wt [kk][p][ks].
// ---------------------------------------------------------------------------
__global__ __launch_bounds__(128) void prep_kernel(const void* __restrict__ mask_raw,
                                                   const void* __restrict__ msa_mask_raw,
                                                   const float* __restrict__ w_out,
                                                   __bf16* __restrict__ wt,
                                                   float* __restrict__ invp,
                                                   int* __restrict__ cnt,
                                                   int* __restrict__ sperm,
                                                   int* __restrict__ nperm,
                                                   float* __restrict__ mkf) {
  const int blk = blockIdx.x;
  const int tid = threadIdx.x;
  if (blk == 0) {
    __shared__ int sh[128];
    __shared__ float sv[512];
    __shared__ int sp[512];
    __shared__ int csh;
    const unsigned int* u = (const unsigned int*)msa_mask_raw;
    sh[tid] = (u[tid] > 1u) ? 1 : 0;
    __syncthreads();
    for (int off = 64; off > 0; off >>= 1) {
      if (tid < off) sh[tid] |= sh[tid + off];
      __syncthreads();
    }
    const int int_mode = (sh[0] == 0);
    __syncthreads();
    for (int q = tid; q < DS; q += 128) {
      float v;
      if (int_mode) v = (((const int*)msa_mask_raw)[q] != 0) ? 1.f : 0.f;
      else          v = (((const unsigned char*)msa_mask_raw)[q] != 0) ? 1.f : 0.f;
      sv[q] = v;
    }
    __syncthreads();
    if (tid < 64) {
      int base = 0;
#pragma unroll
      for (int r = 0; r < 8; ++r) {
        const int s = r * 64 + tid;
        const bool v = (sv[s] != 0.f);
        const unsigned long long bal = __ballot(v);
        const int below = __popcll(bal & ((1ull << tid) - 1ull));
        if (v) sp[base + below] = s;
        base += __popcll(bal);
      }
      if (tid == 0) {
        csh = base;
        cnt[0] = base;
        float num = (float)base;
        if (num < 1e-5f) num = 1e-5f;
        invp[0] = 1.0f / num;
      }
    }
    __syncthreads();
    const int c = csh;
    for (int q = tid; q < c; q += 128) sperm[q] = sp[q];
  } else if (blk == 1) {
    __shared__ int sh[128];
    __shared__ float sv[384];
    __shared__ int sp[384];
    __shared__ int csh;
    const unsigned int* u = (const unsigned int*)mask_raw;
    sh[tid] = (tid < 96) ? ((u[tid] > 1u) ? 1 : 0) : 0;
    __syncthreads();
    for (int off = 64; off > 0; off >>= 1) {
      if (tid < off) sh[tid] |= sh[tid + off];
      __syncthreads();
    }
    const int int_mode = (sh[0] == 0);
    __syncthreads();
    for (int q = tid; q < DN; q += 128) {
      float v;
      if (int_mode) v = (((const int*)mask_raw)[q] != 0) ? 1.f : 0.f;
      else          v = (((const unsigned char*)mask_raw)[q] != 0) ? 1.f : 0.f;
      sv[q] = v;
      mkf[q] = v;
    }
    __syncthreads();
    if (tid < 64) {
      int base = 0;
#pragma unroll
      for (int r = 0; r < 6; ++r) {
        const int n = r * 64 + tid;
        const bool v = (sv[n] != 0.f);
        const unsigned long long bal = __ballot(v);
        const int below = __popcll(bal & ((1ull << tid) - 1ull));
        if (v) sp[base + below] = n;
        base += __popcll(bal);
      }
      if (tid == 0) {
        csh = base;
        cnt[1] = base;
      }
    }
    __syncthreads();
    const int c = csh;
    for (int q = tid; q < 392; q += 128) nperm[q] = (q < c) ? sp[q] : 0;
  } else {
    const int p = blk - 2;                        // 0..127
    const int kk = tid >> 1, ks0 = (tid & 1) * 8; // 16B run
    bf16x8 pk;
#pragma unroll
    for (int j = 0; j < 8; ++j) {
      const int kp = kk * 16 + ks0 + j;           // k' = e*32+d
      const int d = kp & 31, e = kp >> 5;
      pk[j] = (__bf16)w_out[(size_t)(d * 32 + e) * DP + p];
    }
    *(bf16x8*)(wt + ((size_t)kk * 128 + p) * 16 + ks0) = pk;
  }
}

// ---------------------------------------------------------------------------
// ln_proj: blocks b < 2*ntile8 do compacted LN+projection; remaining blocks
// stream b_out into out (fill, unconditional — streaming-write-bound),
// overlapped with the LN work. Fused overwrites valid pairs afterwards.
// ---------------------------------------------------------------------------
__global__ __launch_bounds__(256) void ln_proj_kernel(const float* __restrict__ msa,
                                                      const float* __restrict__ gamma,
                                                      const float* __restrict__ beta,
                                                      const float* __restrict__ w_hidden,
                                                      const float* __restrict__ invp,
                                                      const int* __restrict__ cnt,
                                                      const int* __restrict__ sperm,
                                                      const int* __restrict__ nperm,
                                                      const float* __restrict__ b_out,
                                                      float* __restrict__ out,
                                                      __bf16* __restrict__ at,
                                                      __bf16* __restrict__ bt) {
  __shared__ __align__(16) char lds[46080];
  char* xlb = lds;            // 256 rows x 144B (64 bf16 + 16B pad)
  char* whb = lds + 36864;    // 64 rows x 144B: wh[c][d] bf16

  const int tid = threadIdx.x;
  const int b = blockIdx.x;

  const int scnt = cnt[0], ncnt = cnt[1];
  const int ntile8 = ((ncnt + 7) >> 3) << 3;

  if (b >= 2 * ntile8) {
    // ---- fill worker: out[i][j][:] = b_out (valid pairs overwritten later) ----
    const int nW = 832 - 2 * ntile8;              // >= 64
    const int fi = b - 2 * ntile8;
    const float4 bv = ((const float4*)b_out)[tid & 31];  // invariant: 256 % 32 == 0
    float4* o4 = (float4*)out;
    const size_t total4 = (size_t)DN * DN * 32;
    for (size_t q = (size_t)fi * 256 + tid; q < total4; q += (size_t)nW * 256)
      o4[q] = bv;
    return;
  }

  const int cn = b >> 1;
  const int hf = b & 1;

  // stage w_hidden^T: wh[c][d] = w_hidden[d][c]
  for (int idx = tid; idx < 4096; idx += 256) {
    const int d = idx >> 6, c = idx & 63;
    *(__bf16*)(whb + c * 144 + d * 2) = (__bf16)w_hidden[idx];
  }

  const int cs = (hf << 8) + tid;
  const bool act = (cn < ncnt) && (cs < scnt);

  if (act) {
    const int n = nperm[cn];
    const int s = sperm[cs];
    const float* mp = msa + ((size_t)s * DN + n) * DMSA;
    float x[64];
    float sum = 0.f, sq = 0.f;
#pragma unroll
    for (int q = 0; q < 16; ++q) {
      float4 v = ((const float4*)mp)[q];
      x[4 * q + 0] = v.x; x[4 * q + 1] = v.y; x[4 * q + 2] = v.z; x[4 * q + 3] = v.w;
      sum += v.x + v.y + v.z + v.w;
      sq  += v.x * v.x + v.y * v.y + v.z * v.z + v.w * v.w;
    }
    const float mu = sum * (1.f / 64.f);
    const float var = sq * (1.f / 64.f) - mu * mu;
    const float rstd = rsqrtf(var + 1e-5f);
#pragma unroll
    for (int c8 = 0; c8 < 8; ++c8) {
      bf16x8 pk;
#pragma unroll
      for (int j = 0; j < 8; ++j) {
        const int d = c8 * 8 + j;
        pk[j] = (__bf16)((x[d] - mu) * rstd * gamma[d] + beta[d]);
      }
      *(bf16x8*)(xlb + tid * 144 + c8 * 16) = pk;
    }
  } else {
    const bf16x8 z = {};
#pragma unroll
    for (int c8 = 0; c8 < 8; ++c8)
      *(bf16x8*)(xlb + tid * 144 + c8 * 16) = z;
  }
  __syncthreads();

  // ---- MFMA: wave w owns rows w*64..+64; C[row=cs][col=c], K=64 ----
  const int l = tid & 63, w = tid >> 6;
  const int lr = l & 15, lk = l >> 4;

  bf16x8 bfr[4][2];
#pragma unroll
  for (int fj = 0; fj < 4; ++fj)
#pragma unroll
    for (int kk = 0; kk < 2; ++kk)
      bfr[fj][kk] = *(const bf16x8*)(whb + (fj * 16 + lr) * 144 + (kk * 4 + lk) * 16);

  f32x4 acc[4][4];
#pragma unroll
  for (int i = 0; i < 4; ++i)
#pragma unroll
    for (int j = 0; j < 4; ++j) acc[i][j] = (f32x4){0.f, 0.f, 0.f, 0.f};

#pragma unroll
  for (int fi = 0; fi < 4; ++fi) {
    bf16x8 af[2];
#pragma unroll
    for (int kk = 0; kk < 2; ++kk)
      af[kk] = *(const bf16x8*)(xlb + (w * 64 + fi * 16 + lr) * 144 + (kk * 4 + lk) * 16);
#pragma unroll
    for (int fj = 0; fj < 4; ++fj)
#pragma unroll
      for (int kk = 0; kk < 2; ++kk)
        acc[fi][fj] = __builtin_amdgcn_mfma_f32_16x16x32_bf16(af[kk], bfr[fj][kk], acc[fi][fj], 0, 0, 0);
  }

  // ---- epilogue: a scaled by inv; packed 8B stores at compacted cs ----
  const float inv = invp[0];
#pragma unroll
  for (int fi = 0; fi < 4; ++fi) {
    const int sg = (hf << 8) + w * 64 + fi * 16 + lk * 4;
#pragma unroll
    for (int fj = 0; fj < 4; ++fj) {
      const int c = fj * 16 + lr;
      bf16x4 pk;
      if (fj < 2) {
#pragma unroll
        for (int r = 0; r < 4; ++r) pk[r] = (__bf16)(acc[fi][fj][r] * inv);
        *(bf16x4*)(at + ((size_t)cn * DH + c) * DS + sg) = pk;
      } else {
#pragma unroll
        for (int r = 0; r < 4; ++r) pk[r] = (__bf16)acc[fi][fj][r];
        *(bf16x4*)(bt + ((size_t)cn * DH + (c - 32)) * DS + sg) = pk;
      }
    }
  }
}

// ---------------------------------------------------------------------------
// fused (r13-best): grid 2304, blocks orig < tiles^2 map via bijective XCD
// swizzle within the active square; rest exit instantly. GEMM1 256x256 x
// K=64*nh coarse dbuf loop -> op->LDS (swizzled) -> GEMM2 (2-window wt
// pipeline) -> scatter epilogue via nperm (invalid pairs -> trash).
// ---------------------------------------------------------------------------
__global__ __launch_bounds__(512, 2) void fused_kernel(const __bf16* __restrict__ at,
                                                       const __bf16* __restrict__ bt,
                                                       const __bf16* __restrict__ wt,
                                                       const int* __restrict__ cnt,
                                                       const int* __restrict__ nperm,
                                                       const float* __restrict__ b_out,
                                                       float* __restrict__ trash,
                                                       float* __restrict__ out) {
  __shared__ __align__(128) char smem[132096];

  const int tid = threadIdx.x;
  const int l = tid & 63, w = tid >> 6;
  const int lr = l & 15, lk = l >> 4;
  const int wr = w >> 2, wc = w & 3;

  const int scnt = cnt[0], ncnt = cnt[1];
  const int tiles = (ncnt + 7) >> 3;
  const int nwg = tiles * tiles;
  const int orig = blockIdx.x;
  if (orig >= nwg) return;

  // bijective XCD swizzle within [0, nwg)
  const int xcd = orig & 7;
  const int qq = nwg >> 3, rr = nwg & 7;
  const int wgid = (xcd < rr ? xcd * (qq + 1) : rr * (qq + 1) + (xcd - rr) * qq) + (orig >> 3);
  const int bx = wgid % tiles;
  const int by = wgid / tiles;

  int nh = (scnt + 63) >> 6;
  if (nh < 1) nh = 1;

  // staging source pointers (pre-swizzled: LDS[row][chl] <- logical chl^(row&7))
  const __bf16* gA[4];
  const __bf16* gB[4];
#pragma unroll
  for (int q = 0; q < 4; ++q) {
    const int idx = q * 512 + tid;
    const int row = idx >> 3, chl = idx & 7;
    const int src = (chl ^ (row & 7)) * 8;
    gA[q] = at + (size_t)(bx * 256 + row) * 512 + src;
    gB[q] = bt + (size_t)(by * 256 + row) * 512 + src;
  }

  f32x4 acc[8][4];
#pragma unroll
  for (int i = 0; i < 8; ++i)
#pragma unroll
    for (int j = 0; j < 4; ++j) acc[i][j] = (f32x4){0.f, 0.f, 0.f, 0.f};

  auto STAGE = [&](int h, int s) {
    char* da = smem + s * 65536 + tid * 16;
    char* db = da + 32768;
    const int go = h * 64;
#pragma unroll
    for (int q = 0; q < 4; ++q) {
      async16(gA[q] + go, da + q * 8192);
      async16(gB[q] + go, db + q * 8192);
    }
  };

  STAGE(0, 0);
  asm volatile("s_waitcnt vmcnt(0)" ::: "memory");
  __builtin_amdgcn_s_barrier();

  for (int h = 0; h < nh; ++h) {
    const char* A = smem + (h & 1) * 65536;
    const char* B = A + 32768;
    if (h + 1 < nh) STAGE(h + 1, (h + 1) & 1);

#pragma unroll
    for (int kk = 0; kk < 2; ++kk) {
      bf16x8 af[8], bfr[4];
      const int c = kk * 4 + lk;
      const int phys = (c ^ (lr & 7)) * 16;
#pragma unroll
      for (int fj = 0; fj < 4; ++fj) {
        const int r = wc * 64 + fj * 16 + lr;
        bfr[fj] = *(const bf16x8*)(B + r * 128 + phys);
      }
#pragma unroll
      for (int fi = 0; fi < 8; ++fi) {
        const int r = wr * 128 + fi * 16 + lr;
        af[fi] = *(const bf16x8*)(A + r * 128 + phys);
      }
#pragma unroll
      for (int fi = 0; fi < 8; ++fi)
#pragma unroll
        for (int fj = 0; fj < 4; ++fj)
          acc[fi][fj] = __builtin_amdgcn_mfma_f32_16x16x32_bf16(af[fi], bfr[fj], acc[fi][fj], 0, 0, 0);
    }

    if (h + 1 < nh) {
      asm volatile("s_waitcnt vmcnt(0)" ::: "memory");
      __builtin_amdgcn_s_barrier();
    }
  }

  asm volatile("" ::: "memory");
  __builtin_amdgcn_s_barrier();
  asm volatile("" ::: "memory");

  // ---- op tile -> LDS bf16 as A2[pair][k'=e*32+d], chunk-XOR swizzled ----
#pragma unroll
  for (int fi = 0; fi < 8; ++fi) {
    const int i_l = wr * 4 + (fi >> 1);
#pragma unroll
    for (int fj = 0; fj < 4; ++fj) {
      const int col = wc * 64 + fj * 16 + lr;
      const int j_l = col >> 5, e = col & 31;
      const int pair = i_l * 8 + j_l;
      const int cw = e * 4 + (fi & 1) * 2 + (lk >> 1);
      const int phys = cw ^ (e & 7);
      bf16x4 pk;
      pk[0] = (__bf16)acc[fi][fj][0];
      pk[1] = (__bf16)acc[fi][fj][1];
      pk[2] = (__bf16)acc[fi][fj][2];
      pk[3] = (__bf16)acc[fi][fj][3];
      *(bf16x4*)(smem + pair * 2064 + phys * 16 + (lk & 1) * 8) = pk;
    }
  }

  // GEMM2 geometry; issue window-0 wt loads before the drain barrier (T14)
  const int mf = w >> 2, pf = w & 3;
  const int l31 = l & 31, lh = l >> 5;
  const __bf16* wb = wt + (size_t)(pf * 32 + l31) * 16 + lh * 8;  // + kk*2048

  bf16x8 bw[8], bn[8];
#pragma unroll
  for (int j = 0; j < 8; ++j)
    bw[j] = *(const bf16x8*)(wb + (size_t)j * 2048);

  asm volatile("s_waitcnt lgkmcnt(0)" ::: "memory");
  __builtin_amdgcn_s_barrier();

  // ---- GEMM2: 2-window (8+8) pipelined, 32x32x16 MFMA ----
  f32x16 acc2v;
#pragma unroll
  for (int q = 0; q < 16; ++q) acc2v[q] = 0.f;

  const char* aBase = smem + (mf * 32 + l31) * 2064;
#pragma unroll
  for (int wnd = 0; wnd < 8; ++wnd) {
    if (wnd < 7) {
#pragma unroll
      for (int j = 0; j < 8; ++j)
        bn[j] = *(const bf16x8*)(wb + (size_t)((wnd + 1) * 8 + j) * 2048);
    }
#pragma unroll
    for (int j = 0; j < 8; ++j) {
      const int kk = wnd * 8 + j;
      const int cw = kk * 2 + lh;
      const int phys = cw ^ ((kk >> 1) & 7);
      const bf16x8 a2 = *(const bf16x8*)(aBase + phys * 16);
      acc2v = __builtin_amdgcn_mfma_f32_32x32x16_bf16(a2, bw[j], acc2v, 0, 0, 0);
    }
#pragma unroll
    for (int j = 0; j < 8; ++j) bw[j] = bn[j];
  }

  // ---- scatter epilogue: valid pairs -> out[nperm[ii]][nperm[jj]] ----
  const int p = pf * 32 + l31;
  const float bo = b_out[p];
#pragma unroll
  for (int reg = 0; reg < 16; ++reg) {
    const int pair = mf * 32 + (reg & 3) + 8 * (reg >> 2) + 4 * lh;
    const int ii = bx * 8 + (pair >> 3);
    const int jj = by * 8 + (pair & 7);
    const bool valid = (ii < ncnt) && (jj < ncnt);
    const int ig = nperm[ii];
    const int jg = nperm[jj];
    float* dst = valid ? (out + ((size_t)ig * DN + jg) * DP + p)
                       : (trash + (tid * 16 + reg));
    *dst = acc2v[reg] + bo;
  }
}

extern "C" void kernel_launch(void* const* d_in, const int* in_sizes, int n_in,
                              void* d_out, int out_size, void* d_ws, size_t ws_size,
                              hipStream_t stream) {
  const float* msa      = (const float*)d_in[0];
  const void*  mask     = d_in[1];
  const void*  msa_mask = d_in[2];
  const float* gamma    = (const float*)d_in[3];
  const float* beta     = (const float*)d_in[4];
  const float* w_hidden = (const float*)d_in[5];
  const float* w_out    = (const float*)d_in[6];
  const float* b_out    = (const float*)d_in[7];
  float* out = (float*)d_out;

  char* ws = (char*)d_ws;
  __bf16* at    = (__bf16*)ws;
  __bf16* bt    = (__bf16*)(ws + OFF_BT);
  __bf16* wt    = (__bf16*)(ws + OFF_WT);
  float*  inv   = (float*)(ws + OFF_INV);
  int*    cnt   = (int*)(ws + OFF_CNT);
  int*    sperm = (int*)(ws + OFF_SPERM);
  int*    nperm = (int*)(ws + OFF_NPERM);
  float*  mkf   = (float*)(ws + OFF_MKF);
  float*  trash = (float*)(ws + OFF_TRASH);

  prep_kernel<<<130, 128, 0, stream>>>(mask, msa_mask, w_out, wt, inv, cnt, sperm, nperm, mkf);
  ln_proj_kernel<<<832, 256, 0, stream>>>(msa, gamma, beta, w_hidden, inv, cnt, sperm, nperm,
                                          b_out, out, at, bt);
  fused_kernel<<<2304, 512, 0, stream>>>(at, bt, wt, cnt, nperm, b_out, trash, out);
}